// Round 16
// baseline (329.206 us; speedup 1.0000x reference)
//
#include <hip/hip_runtime.h>

// out = relu(concat(nf, prompt[bidx]) @ W1 + b1) @ W2 + b2
//   P2   = gp @ W1[512:] + b1                 (tiny)
//   nfbf = bf16(nf)                           (streaming, parked in d_out)
//   h    = relu(nfbf @ W1[:512] + P2[bidx])   (g1)
//   out  = h @ W2 + b2                        (g2)
// Round 16: 256^2-tile 8-wave 2-phase dbuf (T3 recipe: stage(t+1) issued BEFORE
// compute(t); ONE vmcnt(0)+s_barrier per K-step AFTER compute). m230/m248v2
// measured 666-682 TF for this structure vs our 128^2 family's 361-456 TF.

#define N_NODES 100000
#define NWG 782                 // 391 m-tiles * 2 n-tiles; 782 = 6*98 + 2*97

typedef __bf16 bf16x8 __attribute__((ext_vector_type(8)));
typedef float  f32x4  __attribute__((ext_vector_type(4)));
typedef unsigned short ushort_t;

__device__ __forceinline__ ushort_t f2bf(float f) {
  __bf16 b = (__bf16)f;
  return __builtin_bit_cast(unsigned short, b);
}

__device__ __forceinline__ bf16x8 cvt8(const float* p) {
  float4 x = *(const float4*)p;
  float4 y = *(const float4*)(p + 4);
  bf16x8 v;
  v[0] = (__bf16)x.x; v[1] = (__bf16)x.y; v[2] = (__bf16)x.z; v[3] = (__bf16)x.w;
  v[4] = (__bf16)y.x; v[5] = (__bf16)y.y; v[6] = (__bf16)y.z; v[7] = (__bf16)y.w;
  return v;
}

__device__ __forceinline__ void gload_lds16(const void* g, void* l) {
  __builtin_amdgcn_global_load_lds(
      (const __attribute__((address_space(1))) void*)g,
      (__attribute__((address_space(3))) void*)l, 16, 0, 0);
}

// bijective chunked XCD swizzle for NWG=782 (q=97, r=6)
__device__ __forceinline__ int xcd_map(int b) {
  int xcd = b & 7, pos = b >> 3;
  return (xcd < 6 ? xcd * 98 : 588 + (xcd - 6) * 97) + pos;
}

// ---------------- convert: nfbf = bf16(nf), vectorized x8 ----------------
__global__ __launch_bounds__(256) void convert_kernel(const float* __restrict__ nf,
                                                      ushort_t* __restrict__ nfbf) {
  for (int c = blockIdx.x * 256 + threadIdx.x; c < 6400000; c += 2048 * 256)
    *(bf16x8*)(nfbf + (size_t)c * 8) = cvt8(nf + (size_t)c * 8);
}

// ---------------- prep: weight transposes to bf16 ----------------
__global__ void prep_kernel(const float* __restrict__ W1, const float* __restrict__ W2,
                            ushort_t* __restrict__ W1T, ushort_t* __restrict__ W2T) {
  int i = blockIdx.x * 256 + threadIdx.x;
  if (i < 524288) {
    int n = i >> 10, k = i & 1023;
    W1T[i] = f2bf(W1[k * 512 + n]);             // W1T[n*1024+k]
  } else if (i < 786432) {
    int j = i - 524288;
    int n = j >> 9, k = j & 511;
    W2T[j] = f2bf(W2[k * 512 + n]);             // W2T[n*512+k]
  }
}

// ---------------- P2[g][n] = gp[g] @ W1[512:] + bias1 ----------------
__global__ __launch_bounds__(256, 4) void p2_kernel(
    const float* __restrict__ gp, const ushort_t* __restrict__ W1T,
    const float* __restrict__ bias1, float* __restrict__ P2) {
  const int tid = threadIdx.x, lane = tid & 63, wid = tid >> 6;
  const int lc = lane & 15, lr = lane >> 4;
  const int m0 = (blockIdx.x >> 1) * 32;
  const int col0 = (blockIdx.x & 1) * 256 + wid * 64;

  f32x4 acc[2][4];
#pragma unroll
  for (int i = 0; i < 2; ++i)
#pragma unroll
    for (int j = 0; j < 4; ++j) acc[i][j] = {0.f, 0.f, 0.f, 0.f};

  const float* a0 = gp + (size_t)(m0 + lc) * 512;
  const ushort_t* bb = W1T + (size_t)(col0 + lc) * 1024 + 512;

#pragma unroll 2
  for (int kt = 0; kt < 8; ++kt) {
    bf16x8 bfr[2][4];
#pragma unroll
    for (int kk = 0; kk < 2; ++kk)
#pragma unroll
      for (int j = 0; j < 4; ++j)
        bfr[kk][j] = *(const bf16x8*)(bb + (size_t)j * 16 * 1024 + kt * 64 + kk * 32 + lr * 8);
    bf16x8 af[2][2];
#pragma unroll
    for (int i = 0; i < 2; ++i)
#pragma unroll
      for (int kk = 0; kk < 2; ++kk)
        af[i][kk] = cvt8(a0 + (size_t)i * 16 * 512 + kt * 64 + kk * 32 + lr * 8);
#pragma unroll
    for (int kk = 0; kk < 2; ++kk)
#pragma unroll
      for (int i = 0; i < 2; ++i)
#pragma unroll
        for (int j = 0; j < 4; ++j)
          acc[i][j] = __builtin_amdgcn_mfma_f32_16x16x32_bf16(af[i][kk], bfr[kk][j], acc[i][j], 0, 0, 0);
  }

#pragma unroll
  for (int i = 0; i < 2; ++i)
#pragma unroll
    for (int r = 0; r < 4; ++r) {
      int row = m0 + i * 16 + lr * 4 + r;
#pragma unroll
      for (int j = 0; j < 4; ++j) {
        int col = col0 + j * 16 + lc;
        P2[(size_t)row * 512 + col] = acc[i][j][r] + bias1[col];
      }
    }
}

// ---------------- G1: h = relu(nfbf @ W1a + P2[bidx]); 256^2 2-phase dbuf ----------------
__global__ __launch_bounds__(512, 2) void g1_kernel(
    const ushort_t* __restrict__ nfbf, const int* __restrict__ bidx,
    const ushort_t* __restrict__ W1T, const float* __restrict__ P2,
    ushort_t* __restrict__ h) {
  __shared__ ushort_t sA[2][256 * 64];   // 2 x 32 KB, chunk-swizzled (^row&7)
  __shared__ ushort_t sB[2][256 * 64];   // 2 x 32 KB  (total 128 KB)

  const int tid = threadIdx.x, lane = tid & 63, wid = tid >> 6;
  const int wg = xcd_map(blockIdx.x);
  const int m0 = (wg >> 1) * 256, n0 = (wg & 1) * 256;

  // staging: 4 chunks (16B) per thread per operand; 2048 chunks cover 256x64
  const ushort_t* pA[4]; const ushort_t* pB[4]; int ldsS[4];
#pragma unroll
  for (int s = 0; s < 4; ++s) {
    int q = s * 512 + tid;
    int row = q >> 3;
    int cw = (q & 7) ^ (row & 7);
    int rowg = m0 + row; if (rowg > N_NODES - 1) rowg = N_NODES - 1;
    pA[s] = nfbf + (size_t)rowg * 512 + cw * 8;
    pB[s] = W1T + (size_t)(n0 + row) * 1024 + cw * 8;
    ldsS[s] = (s * 512 + wid * 64) * 8;   // wave-uniform base; lane*16B implicit
  }

  f32x4 acc[8][4];
#pragma unroll
  for (int i = 0; i < 8; ++i)
#pragma unroll
    for (int j = 0; j < 4; ++j) acc[i][j] = {0.f, 0.f, 0.f, 0.f};

  const int wm = (wid >> 2) * 128;      // 2 m-groups of 128 rows
  const int wn = (wid & 3) * 64;        // 4 n-groups of 64 cols
  const int lr = lane >> 4, lc = lane & 15;

  // prologue: stage tile 0
#pragma unroll
  for (int s = 0; s < 4; ++s) {
    gload_lds16(pA[s], &sA[0][ldsS[s]]); pA[s] += 64;
    gload_lds16(pB[s], &sB[0][ldsS[s]]); pB[s] += 64;
  }
  asm volatile("s_waitcnt vmcnt(0)" ::: "memory");
  __builtin_amdgcn_s_barrier();
  __builtin_amdgcn_sched_barrier(0);

  int cur = 0;
#pragma unroll
  for (int kt = 0; kt < 8; ++kt) {
    // STAGE(t+1) issued BEFORE compute (T3)
    if (kt < 7) {
#pragma unroll
      for (int s = 0; s < 4; ++s) {
        gload_lds16(pA[s], &sA[cur ^ 1][ldsS[s]]); pA[s] += 64;
        gload_lds16(pB[s], &sB[cur ^ 1][ldsS[s]]); pB[s] += 64;
      }
    }
    // compute(t): 64 MFMA per wave
    __builtin_amdgcn_s_setprio(1);
#pragma unroll
    for (int kk = 0; kk < 2; ++kk) {
      bf16x8 bfr[4];
#pragma unroll
      for (int j = 0; j < 4; ++j) {
        int col = wn + j * 16 + lc;
        int cp = (kk * 4 + lr) ^ (col & 7);
        bfr[j] = *(const bf16x8*)&sB[cur][col * 64 + cp * 8];
      }
#pragma unroll
      for (int i = 0; i < 8; ++i) {
        int row = wm + i * 16 + lc;
        int cp = (kk * 4 + lr) ^ (row & 7);
        bf16x8 af = *(const bf16x8*)&sA[cur][row * 64 + cp * 8];
#pragma unroll
        for (int j = 0; j < 4; ++j)
          acc[i][j] = __builtin_amdgcn_mfma_f32_16x16x32_bf16(af, bfr[j], acc[i][j], 0, 0, 0);
      }
    }
    __builtin_amdgcn_s_setprio(0);
    // ONE drain+barrier per K-step, AFTER compute: stage(t+1) loads aged a full phase
    if (kt < 7) {
      asm volatile("s_waitcnt vmcnt(0)" ::: "memory");
      __builtin_amdgcn_s_barrier();
      __builtin_amdgcn_sched_barrier(0);
      cur ^= 1;
    }
  }

  // epilogue: + P2[bidx[row]], relu, bf16 store
#pragma unroll
  for (int i = 0; i < 8; ++i) {
#pragma unroll
    for (int r = 0; r < 4; ++r) {
      int row = m0 + wm + i * 16 + lr * 4 + r;
      if (row < N_NODES) {
        int g = bidx[row];
        const float* p2r = P2 + (size_t)g * 512 + n0 + wn;
#pragma unroll
        for (int j = 0; j < 4; ++j) {
          float v = fmaxf(acc[i][j][r] + p2r[j * 16 + lc], 0.f);
          h[(size_t)row * 512 + n0 + wn + j * 16 + lc] = f2bf(v);
        }
      }
    }
  }
}

// ---------------- G2: out = h @ W2 + b2 (f32); 256^2 2-phase dbuf ----------------
__global__ __launch_bounds__(512, 2) void g2_kernel(
    const ushort_t* __restrict__ h, const ushort_t* __restrict__ W2T,
    const float* __restrict__ bias2, float* __restrict__ out) {
  __shared__ ushort_t sA[2][256 * 64];
  __shared__ ushort_t sB[2][256 * 64];

  const int tid = threadIdx.x, lane = tid & 63, wid = tid >> 6;
  const int wg = xcd_map(blockIdx.x);
  const int m0 = (wg >> 1) * 256, n0 = (wg & 1) * 256;

  const ushort_t* pA[4]; const ushort_t* pB[4]; int ldsS[4];
#pragma unroll
  for (int s = 0; s < 4; ++s) {
    int q = s * 512 + tid;
    int row = q >> 3;
    int cw = (q & 7) ^ (row & 7);
    int rowg = m0 + row; if (rowg > N_NODES - 1) rowg = N_NODES - 1;
    pA[s] = h + (size_t)rowg * 512 + cw * 8;
    pB[s] = W2T + (size_t)(n0 + row) * 512 + cw * 8;
    ldsS[s] = (s * 512 + wid * 64) * 8;
  }

  f32x4 acc[8][4];
#pragma unroll
  for (int i = 0; i < 8; ++i)
#pragma unroll
    for (int j = 0; j < 4; ++j) acc[i][j] = {0.f, 0.f, 0.f, 0.f};

  const int wm = (wid >> 2) * 128;
  const int wn = (wid & 3) * 64;
  const int lr = lane >> 4, lc = lane & 15;

#pragma unroll
  for (int s = 0; s < 4; ++s) {
    gload_lds16(pA[s], &sA[0][ldsS[s]]); pA[s] += 64;
    gload_lds16(pB[s], &sB[0][ldsS[s]]); pB[s] += 64;
  }
  asm volatile("s_waitcnt vmcnt(0)" ::: "memory");
  __builtin_amdgcn_s_barrier();
  __builtin_amdgcn_sched_barrier(0);

  int cur = 0;
#pragma unroll
  for (int kt = 0; kt < 8; ++kt) {
    if (kt < 7) {
#pragma unroll
      for (int s = 0; s < 4; ++s) {
        gload_lds16(pA[s], &sA[cur ^ 1][ldsS[s]]); pA[s] += 64;
        gload_lds16(pB[s], &sB[cur ^ 1][ldsS[s]]); pB[s] += 64;
      }
    }
    __builtin_amdgcn_s_setprio(1);
#pragma unroll
    for (int kk = 0; kk < 2; ++kk) {
      bf16x8 bfr[4];
#pragma unroll
      for (int j = 0; j < 4; ++j) {
        int col = wn + j * 16 + lc;
        int cp = (kk * 4 + lr) ^ (col & 7);
        bfr[j] = *(const bf16x8*)&sB[cur][col * 64 + cp * 8];
      }
#pragma unroll
      for (int i = 0; i < 8; ++i) {
        int row = wm + i * 16 + lc;
        int cp = (kk * 4 + lr) ^ (row & 7);
        bf16x8 af = *(const bf16x8*)&sA[cur][row * 64 + cp * 8];
#pragma unroll
        for (int j = 0; j < 4; ++j)
          acc[i][j] = __builtin_amdgcn_mfma_f32_16x16x32_bf16(af, bfr[j], acc[i][j], 0, 0, 0);
      }
    }
    __builtin_amdgcn_s_setprio(0);
    if (kt < 7) {
      asm volatile("s_waitcnt vmcnt(0)" ::: "memory");
      __builtin_amdgcn_s_barrier();
      __builtin_amdgcn_sched_barrier(0);
      cur ^= 1;
    }
  }

#pragma unroll
  for (int j = 0; j < 4; ++j) {
    int col = n0 + wn + j * 16 + lc;
    float bv = bias2[col];
#pragma unroll
    for (int i = 0; i < 8; ++i)
#pragma unroll
      for (int r = 0; r < 4; ++r) {
        int row = m0 + wm + i * 16 + lr * 4 + r;
        if (row < N_NODES) out[(size_t)row * 512 + col] = acc[i][j][r] + bv;
      }
  }
}

extern "C" void kernel_launch(void* const* d_in, const int* in_sizes, int n_in,
                              void* d_out, int out_size, void* d_ws, size_t ws_size,
                              hipStream_t stream) {
  const float* nf   = (const float*)d_in[0];   // [100000,512] f32
  const float* gp   = (const float*)d_in[1];   // [1024,512]  f32
  const int*   bidx = (const int*)d_in[2];     // [100000]    i32
  const float* W1   = (const float*)d_in[3];   // [1024,512]  f32
  const float* b1   = (const float*)d_in[4];   // [512]
  const float* W2   = (const float*)d_in[5];   // [512,512]   f32
  const float* b2   = (const float*)d_in[6];   // [512]
  float* out = (float*)d_out;

  char* ws = (char*)d_ws;
  ushort_t* W1T = (ushort_t*)ws;                  // 1,048,576 B
  ushort_t* W2T = (ushort_t*)(ws + 1048576);      //   524,288 B
  float*    P2  = (float*)   (ws + 1572864);      // 2,097,152 B
  ushort_t* hbf = (ushort_t*)(ws + 3670016);      // 102,400,000 B (total ~106 MB)

  // nfbf parked in d_out (bf16, 102.4 MB); dead after g1, overwritten by g2.
  ushort_t* nfbf = (ushort_t*)d_out;

  convert_kernel<<<2048, 256, 0, stream>>>(nf, nfbf);
  prep_kernel<<<3072, 256, 0, stream>>>(W1, W2, W1T, W2T);
  p2_kernel<<<64, 256, 0, stream>>>(gp, W1T, b1, P2);
  g1_kernel<<<NWG, 512, 0, stream>>>(nfbf, bidx, W1T, P2, hbf);
  g2_kernel<<<NWG, 512, 0, stream>>>(hbf, W2T, b2, out);
}